// Round 3
// baseline (1232.346 us; speedup 1.0000x reference)
//
#include <hip/hip_runtime.h>
#include <math.h>

#define NN 4096
#define STRIPS 32
#define SW 128                        // strip width (columns per workgroup)
#define RING_ROWS 128                 // power of 2: ring slot = row & 127
#define BATCH 16
#define NSTEPS (NN + 63)              // last needed step t = NN-1+63 = 4158
#define INFV 1e30f
#define SENTU 0xFFFFFFFFu             // memset(0xFF) sentinel, never a DP result

// lane l <- lane l-1 (whole-wave shift right by 1), VALU-latency cross-lane move
__device__ __forceinline__ float dpp_wave_shr1(float x) {
    return __int_as_float(__builtin_amdgcn_update_dpp(
        0, __float_as_int(x), 0x138 /*WAVE_SHR1*/, 0xf, 0xf, false));
}

// lanes 0..15 load boundary rows [row, row+16) of the left strip's column
__device__ __forceinline__ float bload(const unsigned* colL, int row, int lane) {
    float v = INFV;
    if (lane < 16 && row < NN) {
        unsigned u = __hip_atomic_load(colL + row, __ATOMIC_RELAXED,
                                       __HIP_MEMORY_SCOPE_AGENT);
        v = __uint_as_float(u);
    }
    return v;
}

// async-stage rows [rb, rb+16) (128 cols) into the LDS ring at slot (row&127).
// One global_load_lds (16B/lane) covers 2 rows (lanes 0-31 row r0, 32-63 r0+1).
// rb is even; slot pairs never wrap mid-instruction (RING_ROWS even).
__device__ __forceinline__ void stage16(const float* Dg, float* ring, int rb,
                                        int lane) {
    #pragma unroll
    for (int k = 0; k < 8; ++k) {
        const int r0 = rb + 2 * k;
        if (r0 < NN) {
            const int slot = r0 & (RING_ROWS - 1);
            const float* gsrc =
                Dg + (size_t)(r0 + (lane >> 5)) * NN + ((lane & 31) << 2);
            __builtin_amdgcn_global_load_lds(
                (const __attribute__((address_space(1))) unsigned*)gsrc,
                (__attribute__((address_space(3))) unsigned*)((char*)ring +
                                                             slot * (SW * 4)),
                16, 0, 0);
        }
    }
}

// ---------------------------------------------------------------------------
// DP: 32 workgroups x 1 wave. Strip g owns cols [128g, 128g+128); lane l owns
// cols 2l, 2l+1. At step t lane l computes row r = t - l (2 cells). Left/diag
// neighbor values via DPP wave_shr1 (register chain); strip boundary values
// via sentinel-validated agent-scope loads, prefetched one batch ahead.
// Batch structure: [vmcnt guard][spin+swap boundary][stage +2 batches]
//                  [16 grouped ds_reads][16-step register compute].
// ---------------------------------------------------------------------------
__global__ __launch_bounds__(64) void dtw_dp(const float* __restrict__ D,
                                             float* __restrict__ cost_out,
                                             unsigned* __restrict__ colbuf) {
    __shared__ float ring[RING_ROWS * SW];   // 64 KB

    const int g = blockIdx.x;
    const int lane = threadIdx.x;
    const float* Dg = D + g * SW;
    const unsigned* colLu = colbuf + (size_t)(g - 1) * NN;
    unsigned* colMu = colbuf + (size_t)g * NN;
    const bool lane0 = (lane == 0);
    const bool pub = (lane == 63) && (g < STRIPS - 1);
    const bool last = (g == STRIPS - 1) && (lane == 63);

    // prologue: stage rows [0,32) (2 batches ahead), prefetch boundary [0,16)
    stage16(Dg, ring, 0, lane);
    stage16(Dg, ring, 16, lane);
    float bvn = (g > 0) ? bload(colLu, lane, lane) : INFV;

    float cur0 = INFV, cur1 = INFV;   // my c[r-1][2l], c[r-1][2l+1]
    float l1s = INFV, l2s = INFV;     // lane l-1's c1 from t-1, t-2
    float bprev = INFV, bv = INFV;    // boundary regs

    for (int tb = 0; tb < NN + 64; tb += BATCH) {   // 260 batches
        if (g > 0) {
            // validate rows [tb, tb+16) (prefetched last batch); spin if behind
            while (__any((lane < 16) && ((tb + lane) < NN) &&
                         (__float_as_uint(bvn) == SENTU))) {
                bvn = bload(colLu, tb + lane, lane);
            }
            bv = bvn;
            bvn = bload(colLu, tb + BATCH + lane, lane);  // prefetch next batch
        }

        // stage rows [tb+32, tb+48), then guarantee rows [tb, tb+16) (staged
        // two batches ago) have landed. vmcnt(16) is exact for strip 0
        // (16 newer stage ops) and conservative for all others. Tail batches
        // issue partial/empty stages -> count breaks -> full drain (cheap).
        stage16(Dg, ring, tb + 32, lane);
        __builtin_amdgcn_sched_barrier(0);
        if (tb + 46 < NN) {
            asm volatile("s_waitcnt vmcnt(16)" ::: "memory");
        } else {
            asm volatile("s_waitcnt vmcnt(0)" ::: "memory");
        }
        __builtin_amdgcn_sched_barrier(0);

        // grouped LDS -> register reads for the whole batch
        float2 rv[BATCH];
        #pragma unroll
        for (int s = 0; s < BATCH; ++s) {
            const int r = tb + s - lane;
            rv[s] = *reinterpret_cast<const float2*>(
                &ring[(r & (RING_ROWS - 1)) * SW + 2 * lane]);
        }
        __builtin_amdgcn_sched_barrier(0);

        #pragma unroll
        for (int s = 0; s < BATCH; ++s) {
            const int rl = tb + s - lane;
            const bool r0row = (rl == 0);
            const float e0 = __expf(-rv[s].x);
            const float e1 = __expf(-rv[s].y);

            // boundary value for lane 0 (row tb+s), off-chain
            float bcur;
            if (g > 0)
                bcur = __int_as_float(
                    __builtin_amdgcn_readlane(__float_as_int(bv), s));
            else
                bcur = r0row ? 0.f : INFV;     // strip 0: corner cell only

            // off-critical-path INF substitutions for the row-0 special case
            const float L2   = lane0 ? bprev : l2s;
            const float cur0p = r0row ? INFV : cur0;
            const float L2p   = r0row ? INFV : L2;
            const float minrp = r0row ? INFV : fminf(cur0, cur1);

            // critical chain: cnd -> min3 -> add -> fmin -> add -> dpp
            const float L1 = lane0 ? bcur : l1s;               // c[r][col-1]
            const float m0 = fminf(fminf(L1, cur0p), L2p);     // v_min3_f32
            const float c0 = e0 + m0;
            const float c1 = e1 + fminf(c0, minrp);
            cur0 = c0; cur1 = c1;

            if (pub && (unsigned)rl < (unsigned)NN)
                __hip_atomic_store(colMu + rl, __float_as_uint(c1),
                                   __ATOMIC_RELAXED, __HIP_MEMORY_SCOPE_AGENT);
            if (last && rl == NN - 1) cost_out[0] = c1;

            const float sh = dpp_wave_shr1(c1);    // to lane l+1 next step
            l2s = l1s; l1s = sh;
            bprev = bcur;
        }
    }
}

// ---------------------------------------------------------------------------
// acc_grad[i,j] = d[i+1,j+1] + d[i+1,j] + d[i,j+1] - d[i,j],  d = exp(-exp(-D))
// (zero-padded bottom/right). Unchanged from rounds 1-2 (passed, fast).
// ---------------------------------------------------------------------------
__device__ __forceinline__ float dfun(float x) { return __expf(-__expf(-x)); }

__global__ __launch_bounds__(256) void dtw_grad_kernel(const float* __restrict__ D,
                                                       float* __restrict__ G) {
    const int idx = blockIdx.x * 256 + threadIdx.x;
    const int i = idx >> 10;
    const int j = (idx & 1023) << 2;
    if (i >= NN) return;

    const float* row0 = D + (size_t)i * NN + j;
    const bool hasR = (i + 1) < NN;
    const bool hasC = (j + 4) < NN;

    const float4 r0 = *reinterpret_cast<const float4*>(row0);
    float4 r1 = make_float4(0.f, 0.f, 0.f, 0.f);
    if (hasR) r1 = *reinterpret_cast<const float4*>(row0 + NN);
    const float s0 = hasC ? row0[4] : 0.f;
    const float s1 = (hasR && hasC) ? row0[NN + 4] : 0.f;

    const float a0 = dfun(r0.x), a1 = dfun(r0.y), a2 = dfun(r0.z), a3 = dfun(r0.w);
    const float a4 = hasC ? dfun(s0) : 0.f;
    const float b0 = hasR ? dfun(r1.x) : 0.f;
    const float b1 = hasR ? dfun(r1.y) : 0.f;
    const float b2 = hasR ? dfun(r1.z) : 0.f;
    const float b3 = hasR ? dfun(r1.w) : 0.f;
    const float b4 = (hasR && hasC) ? dfun(s1) : 0.f;

    float* go = G + (size_t)i * NN + j;
    go[0] = b1 + b0 + a1 - a0;
    go[1] = b2 + b1 + a2 - a1;
    go[2] = b3 + b2 + a3 - a2;
    go[3] = b4 + b3 + a4 - a3;
}

// ---------------------------------------------------------------------------
extern "C" void kernel_launch(void* const* d_in, const int* in_sizes, int n_in,
                              void* d_out, int out_size, void* d_ws, size_t ws_size,
                              hipStream_t stream) {
    (void)in_sizes; (void)n_in; (void)out_size;
    const float* D = (const float*)d_in[0];
    float* out = (float*)d_out;

    const size_t need = (size_t)STRIPS * NN * sizeof(unsigned);
    unsigned* colbuf = (ws_size >= need) ? (unsigned*)d_ws : (unsigned*)(out + 1);

    // sentinel-fill boundary buffer (sync is "value != 0xFFFFFFFF")
    hipMemsetAsync(colbuf, 0xFF, need, stream);
    dtw_dp<<<STRIPS, 64, 0, stream>>>(D, out, colbuf);
    dtw_grad_kernel<<<dim3((NN * (NN / 4)) / 256), dim3(256), 0, stream>>>(D, out + 1);
}